// Round 1
// baseline (178.587 us; speedup 1.0000x reference)
//
#include <hip/hip_runtime.h>

// SSIM (7x7 uniform window) over B=64, C=1, H=W=384 fp32 images.
// out = mean over interior 378x378 crop of all 64 images (scalar).
//
// Kernel 1: max(gt)            -> ws[0] (monotone-encoded uint)
// Kernel 2: fused separable box-filter SSIM + double accumulation -> ws[8..15]
// Kernel 3: scalar finalize    -> d_out[0]

#define PADW 3
#define WINW 7
#define BW 128            // output columns per block (= blockDim.x)
#define BAND 63           // output rows per block
#define NIN (BAND + 6)    // input rows per block (69)

constexpr int B_ = 64, H_ = 384, W_ = 384;
constexpr int OUTD = W_ - 2 * PADW;                       // 378
constexpr double NPIX = (double)B_ * OUTD * OUTD;         // 9,144,576

// monotone float->uint mapping so uint atomicMax == float max (handles sign)
__device__ __forceinline__ unsigned enc_f(float f) {
    unsigned u = __float_as_uint(f);
    return (u & 0x80000000u) ? ~u : (u | 0x80000000u);
}
__device__ __forceinline__ float dec_f(unsigned e) {
    return __uint_as_float((e & 0x80000000u) ? (e & 0x7fffffffu) : ~e);
}

__global__ void __launch_bounds__(256)
max_kernel(const float4* __restrict__ g4, unsigned* ws_max, int n4) {
    int tid = blockIdx.x * blockDim.x + threadIdx.x;
    int stride = gridDim.x * blockDim.x;
    float m = -3.402823466e38f;
    for (int i = tid; i < n4; i += stride) {
        float4 v = g4[i];
        m = fmaxf(m, fmaxf(fmaxf(v.x, v.y), fmaxf(v.z, v.w)));
    }
#pragma unroll
    for (int off = 32; off > 0; off >>= 1)
        m = fmaxf(m, __shfl_down(m, off));
    __shared__ float sm[4];
    if ((threadIdx.x & 63) == 0) sm[threadIdx.x >> 6] = m;
    __syncthreads();
    if (threadIdx.x == 0) {
        float mm = fmaxf(fmaxf(sm[0], sm[1]), fmaxf(sm[2], sm[3]));
        atomicMax(ws_max, enc_f(mm));
    }
}

__global__ void __launch_bounds__(BW)
ssim_kernel(const float* __restrict__ gt, const float* __restrict__ pred,
            const unsigned* __restrict__ ws_max, double* ws_sum) {
    const int t    = threadIdx.x;
    const int tile = blockIdx.x;   // 0..2 column tiles
    const int band = blockIdx.y;   // 0..5 row bands
    const int b    = blockIdx.z;   // 0..63 images

    const float dr     = dec_f(*ws_max);
    const float C1     = (0.01f * dr) * (0.01f * dr);
    const float C2     = (0.03f * dr) * (0.03f * dr);
    const float inv49  = 1.0f / 49.0f;
    const float covn   = 49.0f / 48.0f;

    const int w0    = PADW + tile * BW;          // first output col of tile
    const int cb    = w0 - PADW;                 // first input col
    const int ncols = min(BW + 6, W_ - cb);      // input cols to stage (134 or 128)
    const int row0  = band * BAND;               // first input row
    const int wcol  = w0 + t;                    // this thread's output column
    const bool active = (wcol <= W_ - 1 - PADW); // cols 3..380 are valid outputs

    __shared__ float sg[BW + 6];
    __shared__ float sp[BW + 6];
    // vertical ring of horizontal sums; ring[slot][quantity][thread].
    // thread-private column -> no sync needed, LDS only to allow dynamic slot idx.
    __shared__ float ring[7][5][BW];
    __shared__ double sred[2];

#pragma unroll
    for (int s = 0; s < 7; ++s)
#pragma unroll
        for (int q = 0; q < 5; ++q)
            ring[s][q][t] = 0.0f;

    float vx = 0.f, vy = 0.f, vxx = 0.f, vyy = 0.f, vxy = 0.f; // sliding vertical sums
    double acc = 0.0;

    const float* gbase = gt   + (size_t)b * H_ * W_;
    const float* pbase = pred + (size_t)b * H_ * W_;

    for (int i = 0; i < NIN; ++i) {
        const int ir = row0 + i;
        __syncthreads();   // protect previous iteration's sg/sp reads
        for (int idx = t; idx < ncols; idx += BW) {
            sg[idx] = gbase[(size_t)ir * W_ + cb + idx];
            sp[idx] = pbase[(size_t)ir * W_ + cb + idx];
        }
        __syncthreads();

        // horizontal 7-tap sums of x, y, x^2, y^2, xy
        float hx = 0.f, hy = 0.f, hxx = 0.f, hyy = 0.f, hxy = 0.f;
#pragma unroll
        for (int k = 0; k < 7; ++k) {
            float g = sg[t + k], p = sp[t + k];
            hx += g; hy += p;
            hxx = fmaf(g, g, hxx);
            hyy = fmaf(p, p, hyy);
            hxy = fmaf(g, p, hxy);
        }

        const int slot = i % 7;
        float ox  = ring[slot][0][t], oy  = ring[slot][1][t];
        float oxx = ring[slot][2][t], oyy = ring[slot][3][t];
        float oxy = ring[slot][4][t];
        ring[slot][0][t] = hx;  ring[slot][1][t] = hy;
        ring[slot][2][t] = hxx; ring[slot][3][t] = hyy;
        ring[slot][4][t] = hxy;
        vx  += hx  - ox;  vy  += hy  - oy;
        vxx += hxx - oxx; vyy += hyy - oyy;
        vxy += hxy - oxy;

        if (i >= 6 && active) {
            float ux  = vx * inv49, uy = vy * inv49;
            float uxx = vxx * inv49 - ux * ux;
            float uyy = vyy * inv49 - uy * uy;
            float uxy = vxy * inv49 - ux * uy;
            float vvx = covn * uxx, vvy = covn * uyy, vvxy = covn * uxy;
            float num = (2.0f * ux * uy + C1) * (2.0f * vvxy + C2);
            float den = (ux * ux + uy * uy + C1) * (vvx + vvy + C2);
            acc += (double)(num / den);
        }
    }

    // block reduction (double) -> one f64 atomic per block
#pragma unroll
    for (int off = 32; off > 0; off >>= 1)
        acc += __shfl_down(acc, off);
    if ((t & 63) == 0) sred[t >> 6] = acc;
    __syncthreads();
    if (t == 0) atomicAdd(ws_sum, sred[0] + sred[1]);
}

__global__ void final_kernel(const double* __restrict__ ws_sum, float* __restrict__ out) {
    out[0] = (float)(ws_sum[0] / NPIX);
}

extern "C" void kernel_launch(void* const* d_in, const int* in_sizes, int n_in,
                              void* d_out, int out_size, void* d_ws, size_t ws_size,
                              hipStream_t stream) {
    const float* gt   = (const float*)d_in[0];
    const float* pred = (const float*)d_in[1];
    // d_in[2] is the uniform 1/49 window -> constant-folded into the kernel.
    float* out = (float*)d_out;

    unsigned* ws_max = (unsigned*)d_ws;
    double*   ws_sum = (double*)((char*)d_ws + 8);

    hipMemsetAsync(d_ws, 0, 16, stream);

    const int n4 = B_ * H_ * W_ / 4;  // 2,359,296 float4s
    max_kernel<<<1024, 256, 0, stream>>>((const float4*)gt, ws_max, n4);

    dim3 grid(3, 6, 64);              // col tiles x row bands x images
    ssim_kernel<<<grid, BW, 0, stream>>>(gt, pred, ws_max, ws_sum);

    final_kernel<<<1, 1, 0, stream>>>(ws_sum, out);
}

// Round 2
// 160.783 us; speedup vs baseline: 1.1107x; 1.1107x over previous
//
#include <hip/hip_runtime.h>

// SSIM (7x7 uniform window) over B=64, C=1, H=W=384 fp32 images.
// out = mean over interior 378x378 crop of all 64 images (scalar).
//
// Kernel 1: max(gt)            -> ws[0] (monotone-encoded uint)
// Kernel 2: fused separable box-filter SSIM, register vertical ring
//           (7-row chunks, compile-time slot), double accumulation -> ws[8..15]
// Kernel 3: scalar finalize    -> d_out[0]

#define PADW 3
#define BW 128            // output columns per block (= blockDim.x)
#define BAND 36           // output rows per block
#define NIN (BAND + 6)    // input rows per block (42 = 6 chunks of 7)
#define NCHUNK (NIN / 7)

constexpr int B_ = 64, H_ = 384, W_ = 384;
constexpr int OUTD = W_ - 2 * PADW;                       // 378
constexpr int NBANDS = (OUTD + BAND - 1) / BAND;          // 11
constexpr double NPIX = (double)B_ * OUTD * OUTD;         // 9,144,576

// monotone float->uint mapping so uint atomicMax == float max (handles sign)
__device__ __forceinline__ unsigned enc_f(float f) {
    unsigned u = __float_as_uint(f);
    return (u & 0x80000000u) ? ~u : (u | 0x80000000u);
}
__device__ __forceinline__ float dec_f(unsigned e) {
    return __uint_as_float((e & 0x80000000u) ? (e & 0x7fffffffu) : ~e);
}

__global__ void __launch_bounds__(256)
max_kernel(const float4* __restrict__ g4, unsigned* ws_max, int n4) {
    int tid = blockIdx.x * blockDim.x + threadIdx.x;
    int stride = gridDim.x * blockDim.x;
    float m = -3.402823466e38f;
    for (int i = tid; i < n4; i += stride) {
        float4 v = g4[i];
        m = fmaxf(m, fmaxf(fmaxf(v.x, v.y), fmaxf(v.z, v.w)));
    }
#pragma unroll
    for (int off = 32; off > 0; off >>= 1)
        m = fmaxf(m, __shfl_down(m, off));
    __shared__ float sm[4];
    if ((threadIdx.x & 63) == 0) sm[threadIdx.x >> 6] = m;
    __syncthreads();
    if (threadIdx.x == 0) {
        float mm = fmaxf(fmaxf(sm[0], sm[1]), fmaxf(sm[2], sm[3]));
        atomicMax(ws_max, enc_f(mm));
    }
}

__global__ void __launch_bounds__(BW)
ssim_kernel(const float* __restrict__ gt, const float* __restrict__ pred,
            const unsigned* __restrict__ ws_max, double* ws_sum) {
    const int t    = threadIdx.x;
    const int tile = blockIdx.x;   // 0..2 column tiles
    const int band = blockIdx.y;   // 0..NBANDS-1 row bands
    const int b    = blockIdx.z;   // 0..63 images

    const float dr     = dec_f(*ws_max);
    const float C1     = (0.01f * dr) * (0.01f * dr);
    const float C2     = (0.03f * dr) * (0.03f * dr);
    const float inv49  = 1.0f / 49.0f;
    const float covn   = 49.0f / 48.0f;

    const int w0    = PADW + tile * BW;          // first output col of tile
    const int cb    = w0 - PADW;                 // first input col
    const int extra = min(BW + 6, W_ - cb) - BW; // 6 (tiles 0,1) or 0 (tile 2)
    const int row0  = band * BAND;               // first input row / output row idx
    const int wcol  = w0 + t;                    // this thread's output column
    const bool active = (wcol <= W_ - 1 - PADW); // cols 3..380 are valid outputs

    __shared__ float sg[7][BW + 6];
    __shared__ float sp[7][BW + 6];
    __shared__ double sred[2];

    // vertical ring of horizontal 7-tap sums, in REGISTERS
    // (all indexing compile-time via unrolled loops)
    float rx[7], ry[7], rxx[7], ryy[7], rxy[7];
#pragma unroll
    for (int j = 0; j < 7; ++j) { rx[j]=0.f; ry[j]=0.f; rxx[j]=0.f; ryy[j]=0.f; rxy[j]=0.f; }

    float vx = 0.f, vy = 0.f, vxx = 0.f, vyy = 0.f, vxy = 0.f; // sliding vertical sums
    double acc = 0.0;

    const float* gbase = gt   + (size_t)b * H_ * W_;
    const float* pbase = pred + (size_t)b * H_ * W_;

    for (int c = 0; c < NCHUNK; ++c) {
        const int base_ir = row0 + c * 7;
        __syncthreads();   // protect previous chunk's sg/sp reads
        // stage 7 input rows (clamped at image bottom; clamped rows feed only
        // masked-out outputs)
#pragma unroll
        for (int j = 0; j < 7; ++j) {
            const int ir = min(base_ir + j, H_ - 1);
            const float* gr = gbase + (size_t)ir * W_ + cb;
            const float* pr = pbase + (size_t)ir * W_ + cb;
            sg[j][t] = gr[t];
            sp[j][t] = pr[t];
            if (t < 6) {
                sg[j][BW + t] = (t < extra) ? gr[BW + t] : 0.0f;
                sp[j][BW + t] = (t < extra) ? pr[BW + t] : 0.0f;
            }
        }
        __syncthreads();

#pragma unroll
        for (int j = 0; j < 7; ++j) {
            // horizontal 7-tap sums of x, y, x^2, y^2, xy
            float hx = 0.f, hy = 0.f, hxx = 0.f, hyy = 0.f, hxy = 0.f;
#pragma unroll
            for (int k = 0; k < 7; ++k) {
                float g = sg[j][t + k], p = sp[j][t + k];
                hx += g; hy += p;
                hxx = fmaf(g, g, hxx);
                hyy = fmaf(p, p, hyy);
                hxy = fmaf(g, p, hxy);
            }
            // vertical sliding window: evict slot j, insert new row
            vx  += hx  - rx[j];   rx[j]  = hx;
            vy  += hy  - ry[j];   ry[j]  = hy;
            vxx += hxx - rxx[j];  rxx[j] = hxx;
            vyy += hyy - ryy[j];  ryy[j] = hyy;
            vxy += hxy - rxy[j];  rxy[j] = hxy;

            const int i = c * 7 + j;          // row index within band's input window
            if (i >= 6) {
                const int orow = row0 + i - 6; // output row (0..377 valid)
                if (active && orow < OUTD) {
                    float ux  = vx * inv49, uy = vy * inv49;
                    float uxx = vxx * inv49 - ux * ux;
                    float uyy = vyy * inv49 - uy * uy;
                    float uxy = vxy * inv49 - ux * uy;
                    float vvx = covn * uxx, vvy = covn * uyy, vvxy = covn * uxy;
                    float num = (2.0f * ux * uy + C1) * (2.0f * vvxy + C2);
                    float den = (ux * ux + uy * uy + C1) * (vvx + vvy + C2);
                    acc += (double)(num / den);
                }
            }
        }
    }

    // block reduction (double) -> one f64 atomic per block
#pragma unroll
    for (int off = 32; off > 0; off >>= 1)
        acc += __shfl_down(acc, off);
    if ((t & 63) == 0) sred[t >> 6] = acc;
    __syncthreads();
    if (t == 0) atomicAdd(ws_sum, sred[0] + sred[1]);
}

__global__ void final_kernel(const double* __restrict__ ws_sum, float* __restrict__ out) {
    out[0] = (float)(ws_sum[0] / NPIX);
}

extern "C" void kernel_launch(void* const* d_in, const int* in_sizes, int n_in,
                              void* d_out, int out_size, void* d_ws, size_t ws_size,
                              hipStream_t stream) {
    const float* gt   = (const float*)d_in[0];
    const float* pred = (const float*)d_in[1];
    // d_in[2] is the uniform 1/49 window -> constant-folded into the kernel.
    float* out = (float*)d_out;

    unsigned* ws_max = (unsigned*)d_ws;
    double*   ws_sum = (double*)((char*)d_ws + 8);

    hipMemsetAsync(d_ws, 0, 16, stream);

    const int n4 = B_ * H_ * W_ / 4;  // 2,359,296 float4s
    max_kernel<<<1024, 256, 0, stream>>>((const float4*)gt, ws_max, n4);

    dim3 grid(3, NBANDS, 64);         // col tiles x row bands x images
    ssim_kernel<<<grid, BW, 0, stream>>>(gt, pred, ws_max, ws_sum);

    final_kernel<<<1, 1, 0, stream>>>(ws_sum, out);
}